// Round 1
// baseline (50.027 us; speedup 1.0000x reference)
//
#include <hip/hip_runtime.h>
#include <math.h>

// ---- problem constants (from reference) ----
// SIZE = (60, 270, 480); CHANNELS = 14
// GRID_SIZES = [(60,16,16,8), (30,8,8,4), (15,4,4,2)]
// IDX_MAX = (60,3,5) -> patch = (1,90,96); PADDING = (0,1,1) -> ppad = (1,92,98)
// N_PATCH = 64
// t_embed: [64][1][92][98][14] = 8,078,336 f32
// t_manip: [64][16] = 1,024 f32  (appended after t_embed in d_out)

#define N_PATCH     64
#define PPAD_H      92
#define PPAD_W      98
#define CH          14
#define TOTAL_EMBED (N_PATCH * PPAD_H * PPAD_W * CH)   // 8,078,336
#define TOTAL_MANIP (N_PATCH * 16)

__device__ __forceinline__ float lerp1(float a, float b, float f) {
    return a + f * (b - a);
}

// trilinear sample of grid (Tg,Hg,Wg,Cg) at full-res voxel (t,h,w), channel c.
// Matches jax.image.resize 'trilinear': half-pixel centers, edge clamp.
template <int Tg, int Hg, int Wg, int Cg>
__device__ __forceinline__ float trilerp(const float* __restrict__ g,
                                         int t, int h, int w, int c) {
    const float st = (float)((double)Tg / 60.0);
    const float sh = (float)((double)Hg / 270.0);
    const float sw = (float)((double)Wg / 480.0);

    float xt = ((float)t + 0.5f) * st - 0.5f;
    float xh = ((float)h + 0.5f) * sh - 0.5f;
    float xw = ((float)w + 0.5f) * sw - 0.5f;

    float ftf = floorf(xt), fhf = floorf(xh), fwf = floorf(xw);
    float ft = xt - ftf, fh = xh - fhf, fw = xw - fwf;
    int t0 = (int)ftf, h0 = (int)fhf, w0 = (int)fwf;

    int t0c = min(max(t0, 0), Tg - 1);
    int t1c = min(t0 + 1, Tg - 1);          // t0+1 >= 0 always (x >= -0.5)
    int h0c = min(max(h0, 0), Hg - 1);
    int h1c = min(h0 + 1, Hg - 1);
    int w0c = min(max(w0, 0), Wg - 1);
    int w1c = min(w0 + 1, Wg - 1);

    const int sH = Wg * Cg;
    const int sT = Hg * Wg * Cg;
    const float* p0 = g + (size_t)t0c * sT + c;
    int o00 = h0c * sH + w0c * Cg;
    int o01 = h0c * sH + w1c * Cg;
    int o10 = h1c * sH + w0c * Cg;
    int o11 = h1c * sH + w1c * Cg;

    float a = lerp1(lerp1(p0[o00], p0[o01], fw),
                    lerp1(p0[o10], p0[o11], fw), fh);
    if (Tg == 60) {
        // identity in T: ft == 0 exactly -> skip the second t-plane
        return a;
    }
    const float* p1 = g + (size_t)t1c * sT + c;
    float b = lerp1(lerp1(p1[o00], p1[o01], fw),
                    lerp1(p1[o10], p1[o11], fw), fh);
    return lerp1(a, b, ft);
}

__global__ __launch_bounds__(256) void embed_kernel(
    const int* __restrict__ idx,
    const float* __restrict__ g0,
    const float* __restrict__ g1,
    const float* __restrict__ g2,
    float* __restrict__ out) {
    int e = blockIdx.x * 256 + threadIdx.x;
    if (e >= TOTAL_EMBED) return;

    int c = e % CH;
    int r = e / CH;
    int ww = r % PPAD_W; r /= PPAD_W;
    int hh = r % PPAD_H;
    int n  = r / PPAD_H;

    int it = idx[3 * n + 0];
    int ih = idx[3 * n + 1];
    int iw = idx[3 * n + 2];

    int rh = ih * 90 + hh - 1;   // pad_h = 1
    int rw = iw * 96 + ww - 1;   // pad_w = 1
    // t: patch size 1, pad 0 -> pixel t == it, always in range.

    float val = 0.0f;
    if ((unsigned)rh < 270u && (unsigned)rw < 480u) {
        if (c < 8)        val = trilerp<60, 16, 16, 8>(g0, it, rh, rw, c);
        else if (c < 12)  val = trilerp<30,  8,  8, 4>(g1, it, rh, rw, c - 8);
        else              val = trilerp<15,  4,  4, 2>(g2, it, rh, rw, c - 12);
    }
    out[e] = val;
}

__global__ __launch_bounds__(256) void manip_kernel(
    const int* __restrict__ idx, float* __restrict__ out) {
    int e = blockIdx.x * 256 + threadIdx.x;
    if (e >= TOTAL_MANIP) return;
    int n = e >> 4;
    int j = e & 15;
    int l = j & 7;
    // bases = fl32(2^l * pi) == (float)M_PI * 2^l  (pow-2 scaling is exact)
    float base = (float)M_PI * (float)(1 << l);
    float v = (float)idx[3 * n + 0] * base;   // f32 mul, matches reference
    double dv = (double)v;
    out[e] = (float)((j < 8) ? sin(dv) : cos(dv));
}

extern "C" void kernel_launch(void* const* d_in, const int* in_sizes, int n_in,
                              void* d_out, int out_size, void* d_ws, size_t ws_size,
                              hipStream_t stream) {
    const int*   idx = (const int*)  d_in[0];
    // d_in[1] = idx_max (60,3,5), d_in[2] = padding (0,1,1) -- compile-time constants here
    const float* g0  = (const float*)d_in[3];
    const float* g1  = (const float*)d_in[4];
    const float* g2  = (const float*)d_in[5];
    float* out = (float*)d_out;

    int grid_e = (TOTAL_EMBED + 255) / 256;   // 31,556 exactly
    embed_kernel<<<grid_e, 256, 0, stream>>>(idx, g0, g1, g2, out);

    int grid_m = (TOTAL_MANIP + 255) / 256;   // 4
    manip_kernel<<<grid_m, 256, 0, stream>>>(idx, out + TOTAL_EMBED);
}

// Round 2
// 21.917 us; speedup vs baseline: 2.2826x; 2.2826x over previous
//
#include <hip/hip_runtime.h>
#include <math.h>

// ---- problem constants ----
// SIZE=(60,270,480); CHANNELS=14; GRIDS: (60,16,16,8),(30,8,8,4),(15,4,4,2)
// IDX_MAX=(60,3,5) -> patch=(1,90,96); PADDING=(0,1,1) -> ppad=(1,92,98)
// t_embed: [64][1][92][98][14] = 8,078,336 f32 ; t_manip: [64][16]

#define N_PATCH 64
#define PPAD_H 92
#define PPAD_W 98
#define CH 14
#define PIX_PER_PATCH (PPAD_H * PPAD_W)          // 9016
#define PIX_PER_BLOCK 1024
#define BLOCKS_PER_PATCH ((PIX_PER_PATCH + PIX_PER_BLOCK - 1) / PIX_PER_BLOCK)  // 9
#define TOTAL_EMBED (N_PATCH * PIX_PER_PATCH * CH)
#define TOTAL_MANIP (N_PATCH * 16)

__device__ __forceinline__ float lerpf(float a, float b, float f) {
    return a + f * (b - a);
}

__global__ __launch_bounds__(256) void embed_kernel(
    const int* __restrict__ idx,
    const float* __restrict__ g0,
    const float* __restrict__ g1,
    const float* __restrict__ g2,
    float* __restrict__ out)
{
    __shared__ float s_g0[16 * 16 * 8];   // level-0 plane at t=it (identity in T)
    __shared__ float s_g1[8 * 8 * 4];     // level-1, t-lerp pre-applied
    __shared__ float s_g2[4 * 4 * 2];     // level-2, t-lerp pre-applied
    __shared__ int   s_ho0[3][PPAD_H];    // row offset of h0 (elements), -1 => masked row
    __shared__ int   s_ho1[3][PPAD_H];
    __shared__ float s_hf [3][PPAD_H];
    __shared__ int   s_wo0[3][PPAD_W];    // col offset of w0 (elements), -1 => masked col
    __shared__ int   s_wo1[3][PPAD_W];
    __shared__ float s_wf [3][PPAD_W];

    const int tid = threadIdx.x;
    const int n   = blockIdx.y;
    const int it  = idx[3 * n + 0];
    const int ih  = idx[3 * n + 1];
    const int iw  = idx[3 * n + 2];

    // ---- stage level-0 t-plane: 2048 floats = 512 float4 ----
    {
        const float4* src = (const float4*)(g0 + (size_t)it * (16 * 16 * 8));
        float4* dst = (float4*)s_g0;
        for (int i = tid; i < 512; i += 256) dst[i] = src[i];
    }
    // ---- stage level-1 with t-lerp: 256 floats ----
    {
        const float st = (float)((double)30 / 60.0);
        float xt = ((float)it + 0.5f) * st - 0.5f;
        float ftf = floorf(xt);
        float ft  = xt - ftf;
        int t0 = (int)ftf;
        int t0c = min(max(t0, 0), 29), t1c = min(t0 + 1, 29);
        const float* p0 = g1 + t0c * (8 * 8 * 4);
        const float* p1 = g1 + t1c * (8 * 8 * 4);
        if (tid < 256) s_g1[tid] = lerpf(p0[tid], p1[tid], ft);
    }
    // ---- stage level-2 with t-lerp: 32 floats ----
    {
        const float st = (float)((double)15 / 60.0);
        float xt = ((float)it + 0.5f) * st - 0.5f;
        float ftf = floorf(xt);
        float ft  = xt - ftf;
        int t0 = (int)ftf;
        int t0c = min(max(t0, 0), 14), t1c = min(t0 + 1, 14);
        const float* p0 = g2 + t0c * (4 * 4 * 2);
        const float* p1 = g2 + t1c * (4 * 4 * 2);
        if (tid < 32) s_g2[tid] = lerpf(p0[tid], p1[tid], ft);
    }
    // ---- h LUTs (92 rows x 3 levels) ----
    if (tid < PPAD_H) {
        int rh = ih * 90 + tid - 1;
        bool ok = (unsigned)rh < 270u;
        const int   Hgs[3] = {16, 8, 4};
        const int   rst[3] = {16 * 8, 8 * 4, 4 * 2};   // row strides (elements)
        const float shs[3] = {(float)((double)16 / 270.0),
                              (float)((double)8  / 270.0),
                              (float)((double)4  / 270.0)};
        #pragma unroll
        for (int l = 0; l < 3; ++l) {
            float xh = ((float)rh + 0.5f) * shs[l] - 0.5f;
            float ff = floorf(xh);
            float f  = xh - ff;
            int h0 = (int)ff;
            int h0c = min(max(h0, 0), Hgs[l] - 1);
            int h1c = min(h0 + 1, Hgs[l] - 1);
            s_ho0[l][tid] = ok ? h0c * rst[l] : -1;
            s_ho1[l][tid] = h1c * rst[l];
            s_hf [l][tid] = f;
        }
    }
    // ---- w LUTs (98 cols x 3 levels) ----
    if (tid < PPAD_W) {
        int rw = iw * 96 + tid - 1;
        bool ok = (unsigned)rw < 480u;
        const int   Wgs[3] = {16, 8, 4};
        const int   cst[3] = {8, 4, 2};                // channel strides (elements)
        const float sws[3] = {(float)((double)16 / 480.0),
                              (float)((double)8  / 480.0),
                              (float)((double)4  / 480.0)};
        #pragma unroll
        for (int l = 0; l < 3; ++l) {
            float xw = ((float)rw + 0.5f) * sws[l] - 0.5f;
            float ff = floorf(xw);
            float f  = xw - ff;
            int w0 = (int)ff;
            int w0c = min(max(w0, 0), Wgs[l] - 1);
            int w1c = min(w0 + 1, Wgs[l] - 1);
            s_wo0[l][tid] = ok ? w0c * cst[l] : -1;
            s_wo1[l][tid] = w1c * cst[l];
            s_wf [l][tid] = f;
        }
    }
    __syncthreads();

    const int pstart = blockIdx.x * PIX_PER_BLOCK;
    const int pend   = min(pstart + PIX_PER_BLOCK, PIX_PER_PATCH);
    float* outp = out + (size_t)n * PIX_PER_PATCH * CH;

    for (int p = pstart + tid; p < pend; p += 256) {
        int hh = p / PPAD_W;
        int ww = p - hh * PPAD_W;
        float2* o = (float2*)(outp + (size_t)p * CH);

        int ho0_0 = s_ho0[0][hh];
        int wo0_0 = s_wo0[0][ww];
        if ((ho0_0 | wo0_0) < 0) {
            float2 z = make_float2(0.f, 0.f);
            o[0] = z; o[1] = z; o[2] = z; o[3] = z; o[4] = z; o[5] = z; o[6] = z;
            continue;
        }

        float res[CH];
        // ---- level 0: C=8, two float4 per corner ----
        {
            int ho1 = s_ho1[0][hh], wo1 = s_wo1[0][ww];
            float fh = s_hf[0][hh], fw = s_wf[0][ww];
            const float4* c00 = (const float4*)(s_g0 + ho0_0 + wo0_0);
            const float4* c01 = (const float4*)(s_g0 + ho0_0 + wo1);
            const float4* c10 = (const float4*)(s_g0 + ho1 + wo0_0);
            const float4* c11 = (const float4*)(s_g0 + ho1 + wo1);
            #pragma unroll
            for (int q = 0; q < 2; ++q) {
                float4 a = c00[q], b = c01[q], c = c10[q], d = c11[q];
                res[q * 4 + 0] = lerpf(lerpf(a.x, b.x, fw), lerpf(c.x, d.x, fw), fh);
                res[q * 4 + 1] = lerpf(lerpf(a.y, b.y, fw), lerpf(c.y, d.y, fw), fh);
                res[q * 4 + 2] = lerpf(lerpf(a.z, b.z, fw), lerpf(c.z, d.z, fw), fh);
                res[q * 4 + 3] = lerpf(lerpf(a.w, b.w, fw), lerpf(c.w, d.w, fw), fh);
            }
        }
        // ---- level 1: C=4, one float4 per corner ----
        {
            int ho0 = s_ho0[1][hh], ho1 = s_ho1[1][hh];
            int wo0 = s_wo0[1][ww], wo1 = s_wo1[1][ww];
            float fh = s_hf[1][hh], fw = s_wf[1][ww];
            float4 a = *(const float4*)(s_g1 + ho0 + wo0);
            float4 b = *(const float4*)(s_g1 + ho0 + wo1);
            float4 c = *(const float4*)(s_g1 + ho1 + wo0);
            float4 d = *(const float4*)(s_g1 + ho1 + wo1);
            res[8]  = lerpf(lerpf(a.x, b.x, fw), lerpf(c.x, d.x, fw), fh);
            res[9]  = lerpf(lerpf(a.y, b.y, fw), lerpf(c.y, d.y, fw), fh);
            res[10] = lerpf(lerpf(a.z, b.z, fw), lerpf(c.z, d.z, fw), fh);
            res[11] = lerpf(lerpf(a.w, b.w, fw), lerpf(c.w, d.w, fw), fh);
        }
        // ---- level 2: C=2, one float2 per corner ----
        {
            int ho0 = s_ho0[2][hh], ho1 = s_ho1[2][hh];
            int wo0 = s_wo0[2][ww], wo1 = s_wo1[2][ww];
            float fh = s_hf[2][hh], fw = s_wf[2][ww];
            float2 a = *(const float2*)(s_g2 + ho0 + wo0);
            float2 b = *(const float2*)(s_g2 + ho0 + wo1);
            float2 c = *(const float2*)(s_g2 + ho1 + wo0);
            float2 d = *(const float2*)(s_g2 + ho1 + wo1);
            res[12] = lerpf(lerpf(a.x, b.x, fw), lerpf(c.x, d.x, fw), fh);
            res[13] = lerpf(lerpf(a.y, b.y, fw), lerpf(c.y, d.y, fw), fh);
        }
        // ---- store 14 floats as 7 float2 (8B-aligned: 56B pixel stride) ----
        o[0] = make_float2(res[0],  res[1]);
        o[1] = make_float2(res[2],  res[3]);
        o[2] = make_float2(res[4],  res[5]);
        o[3] = make_float2(res[6],  res[7]);
        o[4] = make_float2(res[8],  res[9]);
        o[5] = make_float2(res[10], res[11]);
        o[6] = make_float2(res[12], res[13]);
    }
}

__global__ __launch_bounds__(256) void manip_kernel(
    const int* __restrict__ idx, float* __restrict__ out) {
    int e = blockIdx.x * 256 + threadIdx.x;
    if (e >= TOTAL_MANIP) return;
    int n = e >> 4;
    int j = e & 15;
    int l = j & 7;
    float base = (float)M_PI * (float)(1 << l);   // fl32(2^l * pi), exact pow-2 scale
    float v = (float)idx[3 * n + 0] * base;       // f32 mul, matches reference
    double dv = (double)v;
    out[e] = (float)((j < 8) ? sin(dv) : cos(dv));
}

extern "C" void kernel_launch(void* const* d_in, const int* in_sizes, int n_in,
                              void* d_out, int out_size, void* d_ws, size_t ws_size,
                              hipStream_t stream) {
    const int*   idx = (const int*)  d_in[0];
    const float* g0  = (const float*)d_in[3];
    const float* g1  = (const float*)d_in[4];
    const float* g2  = (const float*)d_in[5];
    float* out = (float*)d_out;

    dim3 grid(BLOCKS_PER_PATCH, N_PATCH);   // (9, 64)
    embed_kernel<<<grid, 256, 0, stream>>>(idx, g0, g1, g2, out);

    int grid_m = (TOTAL_MANIP + 255) / 256;  // 4
    manip_kernel<<<grid_m, 256, 0, stream>>>(idx, out + TOTAL_EMBED);
}

// Round 3
// 14.308 us; speedup vs baseline: 3.4965x; 1.5318x over previous
//
#include <hip/hip_runtime.h>
#include <math.h>

// ---- problem constants ----
// SIZE=(60,270,480); CHANNELS=14; GRIDS: (60,16,16,8),(30,8,8,4),(15,4,4,2)
// IDX_MAX=(60,3,5) -> patch=(1,90,96); PADDING=(0,1,1) -> ppad=(1,92,98)
// t_embed: [64][1][92][98][14] = 8,078,336 f32 ; t_manip: [64][16]

#define N_PATCH 64
#define PPAD_H 92
#define PPAD_W 98
#define CH 14
#define PIX_PER_PATCH (PPAD_H * PPAD_W)          // 9016
#define PIX_PER_CHUNK 256
#define PIX_PER_BLOCK 512
#define BLOCKS_PER_PATCH ((PIX_PER_PATCH + PIX_PER_BLOCK - 1) / PIX_PER_BLOCK)  // 18
#define TOTAL_EMBED (N_PATCH * PIX_PER_PATCH * CH)
#define TOTAL_MANIP (N_PATCH * 16)

__device__ __forceinline__ float lerpf(float a, float b, float f) {
    return a + f * (b - a);
}

__global__ __launch_bounds__(256) void embed_kernel(
    const int* __restrict__ idx,
    const float* __restrict__ g0,
    const float* __restrict__ g1,
    const float* __restrict__ g2,
    float* __restrict__ out)
{
    __shared__ float s_g0[16 * 16 * 8];   // level-0 plane at t=it (identity in T)
    __shared__ float s_g1[8 * 8 * 4];     // level-1, t-lerp pre-applied
    __shared__ float s_g2[4 * 4 * 2];     // level-2, t-lerp pre-applied
    __shared__ int   s_ho0[3][PPAD_H];    // row offset of h0 (elements), -1 => masked
    __shared__ int   s_ho1[3][PPAD_H];
    __shared__ float s_hf [3][PPAD_H];
    __shared__ int   s_wo0[3][PPAD_W];    // col offset of w0 (elements), -1 => masked
    __shared__ int   s_wo1[3][PPAD_W];
    __shared__ float s_wf [3][PPAD_W];
    __shared__ float s_buf[PIX_PER_CHUNK * CH];   // 3584 f = 14KB transpose buffer

    const int tid = threadIdx.x;
    const int n   = blockIdx.y;
    const int it  = idx[3 * n + 0];
    const int ih  = idx[3 * n + 1];
    const int iw  = idx[3 * n + 2];

    // ---- stage level-0 t-plane: 2048 floats = 512 float4 ----
    {
        const float4* src = (const float4*)(g0 + (size_t)it * (16 * 16 * 8));
        float4* dst = (float4*)s_g0;
        for (int i = tid; i < 512; i += 256) dst[i] = src[i];
    }
    // ---- stage level-1 with t-lerp: 256 floats ----
    {
        float xt = ((float)it + 0.5f) * 0.5f - 0.5f;
        float ftf = floorf(xt);
        float ft  = xt - ftf;
        int t0 = (int)ftf;
        int t0c = min(max(t0, 0), 29), t1c = min(t0 + 1, 29);
        const float* p0 = g1 + t0c * (8 * 8 * 4);
        const float* p1 = g1 + t1c * (8 * 8 * 4);
        if (tid < 256) s_g1[tid] = lerpf(p0[tid], p1[tid], ft);
    }
    // ---- stage level-2 with t-lerp: 32 floats ----
    {
        float xt = ((float)it + 0.5f) * 0.25f - 0.5f;
        float ftf = floorf(xt);
        float ft  = xt - ftf;
        int t0 = (int)ftf;
        int t0c = min(max(t0, 0), 14), t1c = min(t0 + 1, 14);
        const float* p0 = g2 + t0c * (4 * 4 * 2);
        const float* p1 = g2 + t1c * (4 * 4 * 2);
        if (tid < 32) s_g2[tid] = lerpf(p0[tid], p1[tid], ft);
    }
    // ---- h LUTs (92 rows x 3 levels) ----
    if (tid < PPAD_H) {
        int rh = ih * 90 + tid - 1;
        bool ok = (unsigned)rh < 270u;
        const int   Hgs[3] = {16, 8, 4};
        const int   rst[3] = {16 * 8, 8 * 4, 4 * 2};
        const float shs[3] = {(float)((double)16 / 270.0),
                              (float)((double)8  / 270.0),
                              (float)((double)4  / 270.0)};
        #pragma unroll
        for (int l = 0; l < 3; ++l) {
            float xh = ((float)rh + 0.5f) * shs[l] - 0.5f;
            float ff = floorf(xh);
            float f  = xh - ff;
            int h0 = (int)ff;
            int h0c = min(max(h0, 0), Hgs[l] - 1);
            int h1c = min(h0 + 1, Hgs[l] - 1);
            s_ho0[l][tid] = ok ? h0c * rst[l] : -1;
            s_ho1[l][tid] = h1c * rst[l];
            s_hf [l][tid] = f;
        }
    }
    // ---- w LUTs (98 cols x 3 levels) ----
    if (tid < PPAD_W) {
        int rw = iw * 96 + tid - 1;
        bool ok = (unsigned)rw < 480u;
        const int   Wgs[3] = {16, 8, 4};
        const int   cst[3] = {8, 4, 2};
        const float sws[3] = {(float)((double)16 / 480.0),
                              (float)((double)8  / 480.0),
                              (float)((double)4  / 480.0)};
        #pragma unroll
        for (int l = 0; l < 3; ++l) {
            float xw = ((float)rw + 0.5f) * sws[l] - 0.5f;
            float ff = floorf(xw);
            float f  = xw - ff;
            int w0 = (int)ff;
            int w0c = min(max(w0, 0), Wgs[l] - 1);
            int w1c = min(w0 + 1, Wgs[l] - 1);
            s_wo0[l][tid] = ok ? w0c * cst[l] : -1;
            s_wo1[l][tid] = w1c * cst[l];
            s_wf [l][tid] = f;
        }
    }

    // ---- fused manip (one block only): 1024 outputs, f64 sin/cos of f32 arg ----
    if (blockIdx.x == 0 && n == 0) {
        float* om = out + TOTAL_EMBED;
        for (int e = tid; e < TOTAL_MANIP; e += 256) {
            int nn = e >> 4;
            int j  = e & 15;
            int l  = j & 7;
            float base = (float)M_PI * (float)(1 << l);  // fl32(2^l*pi), pow2 exact
            float v = (float)idx[3 * nn + 0] * base;     // f32 mul = reference
            double dv = (double)v;
            om[e] = (float)((j < 8) ? sin(dv) : cos(dv));
        }
    }
    __syncthreads();

    const int pstart = blockIdx.x * PIX_PER_BLOCK;
    const int pend   = min(pstart + PIX_PER_BLOCK, PIX_PER_PATCH);
    float* outp = out + (size_t)n * PIX_PER_PATCH * CH;

    for (int pbase = pstart; pbase < pend; pbase += PIX_PER_CHUNK) {
        const int cnt = min(PIX_PER_CHUNK, pend - pbase);   // always even here
        const int p   = pbase + tid;

        if (tid < cnt) {
            int hh = p / PPAD_W;
            int ww = p - hh * PPAD_W;
            float2* b = (float2*)(s_buf + tid * CH);

            int ho0_0 = s_ho0[0][hh];
            int wo0_0 = s_wo0[0][ww];
            if ((ho0_0 | wo0_0) < 0) {
                float2 z = make_float2(0.f, 0.f);
                b[0] = z; b[1] = z; b[2] = z; b[3] = z; b[4] = z; b[5] = z; b[6] = z;
            } else {
                float res[CH];
                // ---- level 0: C=8 ----
                {
                    int ho1 = s_ho1[0][hh], wo1 = s_wo1[0][ww];
                    float fh = s_hf[0][hh], fw = s_wf[0][ww];
                    const float4* c00 = (const float4*)(s_g0 + ho0_0 + wo0_0);
                    const float4* c01 = (const float4*)(s_g0 + ho0_0 + wo1);
                    const float4* c10 = (const float4*)(s_g0 + ho1 + wo0_0);
                    const float4* c11 = (const float4*)(s_g0 + ho1 + wo1);
                    #pragma unroll
                    for (int q = 0; q < 2; ++q) {
                        float4 a = c00[q], bb = c01[q], c = c10[q], d = c11[q];
                        res[q * 4 + 0] = lerpf(lerpf(a.x, bb.x, fw), lerpf(c.x, d.x, fw), fh);
                        res[q * 4 + 1] = lerpf(lerpf(a.y, bb.y, fw), lerpf(c.y, d.y, fw), fh);
                        res[q * 4 + 2] = lerpf(lerpf(a.z, bb.z, fw), lerpf(c.z, d.z, fw), fh);
                        res[q * 4 + 3] = lerpf(lerpf(a.w, bb.w, fw), lerpf(c.w, d.w, fw), fh);
                    }
                }
                // ---- level 1: C=4 ----
                {
                    int ho0 = s_ho0[1][hh], ho1 = s_ho1[1][hh];
                    int wo0 = s_wo0[1][ww], wo1 = s_wo1[1][ww];
                    float fh = s_hf[1][hh], fw = s_wf[1][ww];
                    float4 a = *(const float4*)(s_g1 + ho0 + wo0);
                    float4 bb = *(const float4*)(s_g1 + ho0 + wo1);
                    float4 c = *(const float4*)(s_g1 + ho1 + wo0);
                    float4 d = *(const float4*)(s_g1 + ho1 + wo1);
                    res[8]  = lerpf(lerpf(a.x, bb.x, fw), lerpf(c.x, d.x, fw), fh);
                    res[9]  = lerpf(lerpf(a.y, bb.y, fw), lerpf(c.y, d.y, fw), fh);
                    res[10] = lerpf(lerpf(a.z, bb.z, fw), lerpf(c.z, d.z, fw), fh);
                    res[11] = lerpf(lerpf(a.w, bb.w, fw), lerpf(c.w, d.w, fw), fh);
                }
                // ---- level 2: C=2 ----
                {
                    int ho0 = s_ho0[2][hh], ho1 = s_ho1[2][hh];
                    int wo0 = s_wo0[2][ww], wo1 = s_wo1[2][ww];
                    float fh = s_hf[2][hh], fw = s_wf[2][ww];
                    float2 a = *(const float2*)(s_g2 + ho0 + wo0);
                    float2 bb = *(const float2*)(s_g2 + ho0 + wo1);
                    float2 c = *(const float2*)(s_g2 + ho1 + wo0);
                    float2 d = *(const float2*)(s_g2 + ho1 + wo1);
                    res[12] = lerpf(lerpf(a.x, bb.x, fw), lerpf(c.x, d.x, fw), fh);
                    res[13] = lerpf(lerpf(a.y, bb.y, fw), lerpf(c.y, d.y, fw), fh);
                }
                b[0] = make_float2(res[0],  res[1]);
                b[1] = make_float2(res[2],  res[3]);
                b[2] = make_float2(res[4],  res[5]);
                b[3] = make_float2(res[6],  res[7]);
                b[4] = make_float2(res[8],  res[9]);
                b[5] = make_float2(res[10], res[11]);
                b[6] = make_float2(res[12], res[13]);
            }
        }
        __syncthreads();

        // ---- coalesced store: cnt*14 floats (divisible by 4; 16B-aligned base) ----
        const int nf4 = cnt * CH / 4;
        const float4* sb = (const float4*)s_buf;
        float4* gb = (float4*)(outp + (size_t)pbase * CH);
        for (int j = tid; j < nf4; j += 256) gb[j] = sb[j];
        __syncthreads();
    }
}

extern "C" void kernel_launch(void* const* d_in, const int* in_sizes, int n_in,
                              void* d_out, int out_size, void* d_ws, size_t ws_size,
                              hipStream_t stream) {
    const int*   idx = (const int*)  d_in[0];
    const float* g0  = (const float*)d_in[3];
    const float* g1  = (const float*)d_in[4];
    const float* g2  = (const float*)d_in[5];
    float* out = (float*)d_out;

    dim3 grid(BLOCKS_PER_PATCH, N_PATCH);   // (18, 64) = 1152 blocks
    embed_kernel<<<grid, 256, 0, stream>>>(idx, g0, g1, g2, out);
}